// Round 1
// baseline (1187.496 us; speedup 1.0000x reference)
//
#include <hip/hip_runtime.h>
#include <hip/hip_bf16.h>

// MoE: N=4096 tokens, D=512, H=2048, E=8 experts, top-2.
// Round 1: correctness-first fp32 grouped-expert implementation.
// Structure: gating (1 wave/token) -> per-expert buckets in ws -> grouped
// expert MLP tiles (TN=16 tokens/block) -> atomicAdd into combined output.

#define N_TOK 4096
#define DIM   512
#define HID   2048
#define NEXP  8
#define TN    16
#define HC    256
#define NCHUNK (HID / HC)

__global__ __launch_bounds__(256) void gating_kernel(
    const float* __restrict__ x, const float* __restrict__ Wg,
    const float* __restrict__ bg,
    int* __restrict__ cnt, int* __restrict__ btok, float* __restrict__ bwt,
    float* __restrict__ usage)
{
    int wave = threadIdx.x >> 6;
    int lane = threadIdx.x & 63;
    int n = blockIdx.x * 4 + wave;

    float acc[NEXP];
#pragma unroll
    for (int e = 0; e < NEXP; ++e) acc[e] = 0.f;

    for (int d = lane; d < DIM; d += 64) {
        float xv = x[n * DIM + d];
        float4 wa = *(const float4*)&Wg[d * NEXP];
        float4 wb = *(const float4*)&Wg[d * NEXP + 4];
        acc[0] += xv * wa.x; acc[1] += xv * wa.y;
        acc[2] += xv * wa.z; acc[3] += xv * wa.w;
        acc[4] += xv * wb.x; acc[5] += xv * wb.y;
        acc[6] += xv * wb.z; acc[7] += xv * wb.w;
    }
#pragma unroll
    for (int m = 32; m >= 1; m >>= 1) {
#pragma unroll
        for (int e = 0; e < NEXP; ++e)
            acc[e] += __shfl_xor(acc[e], m, 64);
    }
    if (lane == 0) {
        float l[NEXP];
#pragma unroll
        for (int e = 0; e < NEXP; ++e) l[e] = acc[e] + bg[e];
        int i0 = 0;
#pragma unroll
        for (int e = 1; e < NEXP; ++e) if (l[e] > l[i0]) i0 = e;
        int i1 = (i0 == 0) ? 1 : 0;
#pragma unroll
        for (int e = 0; e < NEXP; ++e)
            if (e != i0 && l[e] > l[i1]) i1 = e;
        // softmax + top-2 renorm: denominators cancel
        float w0 = 1.f / (1.f + expf(l[i1] - l[i0]));
        float w1 = 1.f - w0;
        int p0 = atomicAdd(&cnt[i0], 1);
        btok[i0 * N_TOK + p0] = n; bwt[i0 * N_TOK + p0] = w0;
        int p1 = atomicAdd(&cnt[i1], 1);
        btok[i1 * N_TOK + p1] = n; bwt[i1 * N_TOK + p1] = w1;
        atomicAdd(&usage[i0], w0);
        atomicAdd(&usage[i1], w1);
    }
}

__global__ __launch_bounds__(256) void expert_kernel(
    const float* __restrict__ x, const float* __restrict__ W1,
    const float* __restrict__ b1, const float* __restrict__ W2,
    const float* __restrict__ b2, const int* __restrict__ cnt,
    const int* __restrict__ btok, const float* __restrict__ bwt,
    float* __restrict__ out)
{
    __shared__ float xs[TN][DIM];     // 32 KB
    __shared__ float h1s[TN][HC];     // 16 KB
    __shared__ int   tok_s[TN];
    __shared__ float wt_s[TN];

    int e = blockIdx.x >> 8;          // 256 tiles per expert (N/TN)
    int tile = blockIdx.x & 255;
    int cn = cnt[e];
    int n0 = tile * TN;
    if (n0 >= cn) return;
    int nt = min(TN, cn - n0);
    int tid = threadIdx.x;

    if (tid < TN) {
        if (tid < nt) {
            tok_s[tid] = btok[e * N_TOK + n0 + tid];
            wt_s[tid]  = bwt[e * N_TOK + n0 + tid];
        } else {
            tok_s[tid] = 0; wt_s[tid] = 0.f;
        }
    }
    __syncthreads();
    for (int idx = tid; idx < TN * DIM; idx += 256) {
        int t = idx >> 9, d = idx & 511;
        xs[t][d] = (t < nt) ? x[tok_s[t] * DIM + d] : 0.f;
    }

    const float* W1e = W1 + (size_t)e * DIM * HID;
    const float* W2e = W2 + (size_t)e * HID * DIM;
    int tg = tid >> 6;       // 0..3
    int lane = tid & 63;     // 0..63

    // fc2 accumulators: thread owns t in {tg,tg+4,tg+8,tg+12}, d in [lane*8, lane*8+8)
    float oacc[4][8];
    {
        float4 ba = *(const float4*)&b2[e * DIM + lane * 8];
        float4 bb = *(const float4*)&b2[e * DIM + lane * 8 + 4];
#pragma unroll
        for (int ti = 0; ti < 4; ++ti) {
            oacc[ti][0] = ba.x; oacc[ti][1] = ba.y; oacc[ti][2] = ba.z; oacc[ti][3] = ba.w;
            oacc[ti][4] = bb.x; oacc[ti][5] = bb.y; oacc[ti][6] = bb.z; oacc[ti][7] = bb.w;
        }
    }
    __syncthreads();   // xs ready

    for (int ch = 0; ch < NCHUNK; ++ch) {
        int h0 = ch * HC;
        // ---- phase 1: h1[t][j] for j in [h0, h0+HC); thread: 4 t x 4 j ----
        float f[4][4];
        {
            float4 b1v = *(const float4*)&b1[e * HID + h0 + lane * 4];
#pragma unroll
            for (int ti = 0; ti < 4; ++ti) {
                f[ti][0] = b1v.x; f[ti][1] = b1v.y; f[ti][2] = b1v.z; f[ti][3] = b1v.w;
            }
        }
        for (int d = 0; d < DIM; ++d) {
            float4 w1v = *(const float4*)&W1e[(size_t)d * HID + h0 + lane * 4];
#pragma unroll
            for (int ti = 0; ti < 4; ++ti) {
                float xv = xs[tg + 4 * ti][d];
                f[ti][0] += xv * w1v.x; f[ti][1] += xv * w1v.y;
                f[ti][2] += xv * w1v.z; f[ti][3] += xv * w1v.w;
            }
        }
        __syncthreads();   // previous chunk's phase-2 readers done
#pragma unroll
        for (int ti = 0; ti < 4; ++ti)
            *(float4*)&h1s[tg + 4 * ti][lane * 4] = make_float4(f[ti][0], f[ti][1], f[ti][2], f[ti][3]);
        __syncthreads();   // h1s ready

        // ---- phase 2: out[t][d] += sum_j h1[t][j] * W2[j][d] ----
        for (int j = 0; j < HC; ++j) {
            const float* w2row = &W2e[(size_t)(h0 + j) * DIM + lane * 8];
            float4 wa = *(const float4*)w2row;
            float4 wb = *(const float4*)(w2row + 4);
#pragma unroll
            for (int ti = 0; ti < 4; ++ti) {
                float hv = h1s[tg + 4 * ti][j];
                oacc[ti][0] += hv * wa.x; oacc[ti][1] += hv * wa.y;
                oacc[ti][2] += hv * wa.z; oacc[ti][3] += hv * wa.w;
                oacc[ti][4] += hv * wb.x; oacc[ti][5] += hv * wb.y;
                oacc[ti][6] += hv * wb.z; oacc[ti][7] += hv * wb.w;
            }
        }
    }

    // epilogue: combined[n] += w * expert_out
#pragma unroll
    for (int ti = 0; ti < 4; ++ti) {
        int t = tg + 4 * ti;
        if (t < nt) {
            float w = wt_s[t];
            float* o = &out[(size_t)tok_s[t] * DIM + lane * 8];
#pragma unroll
            for (int c = 0; c < 8; ++c)
                atomicAdd(&o[c], w * oacc[ti][c]);
        }
    }
}

extern "C" void kernel_launch(void* const* d_in, const int* in_sizes, int n_in,
                              void* d_out, int out_size, void* d_ws, size_t ws_size,
                              hipStream_t stream) {
    const float* x  = (const float*)d_in[0];
    const float* Wg = (const float*)d_in[1];
    const float* bg = (const float*)d_in[2];
    const float* W1 = (const float*)d_in[3];
    const float* b1 = (const float*)d_in[4];
    const float* W2 = (const float*)d_in[5];
    const float* b2 = (const float*)d_in[6];

    float* out   = (float*)d_out;
    float* usage = out + (size_t)N_TOK * DIM;

    int*   cnt  = (int*)d_ws;
    int*   btok = (int*)((char*)d_ws + 256);
    float* bwt  = (float*)((char*)d_ws + 256 + (size_t)NEXP * N_TOK * sizeof(int));

    // d_out / d_ws are poisoned 0xAA before every call — zero what we accumulate into.
    hipMemsetAsync(d_out, 0, (size_t)(N_TOK * DIM + NEXP) * sizeof(float), stream);
    hipMemsetAsync(d_ws, 0, 256, stream);

    gating_kernel<<<N_TOK / 4, 256, 0, stream>>>(x, Wg, bg, cnt, btok, bwt, usage);
    expert_kernel<<<NEXP * (N_TOK / TN), 256, 0, stream>>>(
        x, W1, b1, W2, b2, cnt, btok, bwt, out);
}

// Round 2
// 559.432 us; speedup vs baseline: 2.1227x; 2.1227x over previous
//
#include <hip/hip_runtime.h>
#include <hip/hip_bf16.h>

// MoE: N=4096 tokens, D=512, H=2048, E=8 experts, top-2.
// Round 2: grouped bf16 MFMA GEMMs.
//   cvt x->bf16; transpose-convert W1->[E][H][D], W2->[E][D][H] bf16
//   gating -> compact slot lists (prefix over expert counts, total slots 8192)
//   GEMM1: H1[slot,2048] = X[tok,512] x W1t^T   (gathered A rows)
//   GEMM2: out[tok,512] += w * (H1[slot,2048] x W2t^T + b2)  (fp32 atomics)
// Fallback to the verified round-1 fp32 path if ws_size < 68.1 MiB.

#define N_TOK 4096
#define DIM   512
#define HID   2048
#define NEXP  8
#define TOTSLOT (2 * N_TOK)

typedef __attribute__((ext_vector_type(8))) short short8;
typedef __attribute__((ext_vector_type(4))) float f32x4;

static __device__ __forceinline__ unsigned short f2bf(float f) {
    __hip_bfloat16 b = __float2bfloat16(f);
    return *reinterpret_cast<unsigned short*>(&b);
}

// ---------------------------------------------------------------- gating ----
__global__ __launch_bounds__(256) void gating_kernel(
    const float* __restrict__ x, const float* __restrict__ Wg,
    const float* __restrict__ bg,
    int* __restrict__ cnt, int* __restrict__ te, float* __restrict__ tw,
    float* __restrict__ usage)
{
    int wave = threadIdx.x >> 6;
    int lane = threadIdx.x & 63;
    int n = blockIdx.x * 4 + wave;

    float acc[NEXP];
#pragma unroll
    for (int e = 0; e < NEXP; ++e) acc[e] = 0.f;

    for (int d = lane; d < DIM; d += 64) {
        float xv = x[n * DIM + d];
        float4 wa = *(const float4*)&Wg[d * NEXP];
        float4 wb = *(const float4*)&Wg[d * NEXP + 4];
        acc[0] += xv * wa.x; acc[1] += xv * wa.y;
        acc[2] += xv * wa.z; acc[3] += xv * wa.w;
        acc[4] += xv * wb.x; acc[5] += xv * wb.y;
        acc[6] += xv * wb.z; acc[7] += xv * wb.w;
    }
#pragma unroll
    for (int m = 32; m >= 1; m >>= 1) {
#pragma unroll
        for (int e = 0; e < NEXP; ++e)
            acc[e] += __shfl_xor(acc[e], m, 64);
    }
    if (lane == 0) {
        float l[NEXP];
#pragma unroll
        for (int e = 0; e < NEXP; ++e) l[e] = acc[e] + bg[e];
        int i0 = 0;
#pragma unroll
        for (int e = 1; e < NEXP; ++e) if (l[e] > l[i0]) i0 = e;
        int i1 = (i0 == 0) ? 1 : 0;
#pragma unroll
        for (int e = 0; e < NEXP; ++e)
            if (e != i0 && l[e] > l[i1]) i1 = e;
        float w0 = 1.f / (1.f + expf(l[i1] - l[i0]));
        float w1 = 1.f - w0;
        te[n * 2] = i0; te[n * 2 + 1] = i1;
        tw[n * 2] = w0; tw[n * 2 + 1] = w1;
        atomicAdd(&cnt[i0], 1);
        atomicAdd(&cnt[i1], 1);
        atomicAdd(&usage[i0], w0);
        atomicAdd(&usage[i1], w1);
    }
}

__global__ void prefix_kernel(const int* __restrict__ cnt,
                              int* __restrict__ offs, int* __restrict__ fill)
{
    if (threadIdx.x == 0) {
        int s = 0;
        for (int e = 0; e < NEXP; ++e) { offs[e] = s; s += cnt[e]; }
    }
    if (threadIdx.x < NEXP) fill[threadIdx.x] = 0;
}

__global__ __launch_bounds__(256) void scatter_kernel(
    const int* __restrict__ te, const float* __restrict__ tw,
    const int* __restrict__ offs, int* __restrict__ fill,
    int* __restrict__ btok, float* __restrict__ bwt)
{
    __shared__ int lcnt[NEXP];
    __shared__ int gbase[NEXP];
    int tid = threadIdx.x;
    if (tid < NEXP) lcnt[tid] = 0;
    __syncthreads();
    int n = blockIdx.x * 256 + tid;
    int e0 = te[n * 2], e1 = te[n * 2 + 1];
    int l0 = atomicAdd(&lcnt[e0], 1);
    int l1 = atomicAdd(&lcnt[e1], 1);
    __syncthreads();
    if (tid < NEXP) gbase[tid] = atomicAdd(&fill[tid], lcnt[tid]);
    __syncthreads();
    int s0 = offs[e0] + gbase[e0] + l0;
    int s1 = offs[e1] + gbase[e1] + l1;
    btok[s0] = n; bwt[s0] = tw[n * 2];
    btok[s1] = n; bwt[s1] = tw[n * 2 + 1];
}

// ----------------------------------------------------------- conversions ----
__global__ __launch_bounds__(256) void cvtx_kernel(
    const float* __restrict__ x, unsigned short* __restrict__ Xb)
{
    int i = (blockIdx.x * 256 + threadIdx.x) * 4;
    float4 v = *(const float4*)&x[i];
    ushort4 u;
    u.x = f2bf(v.x); u.y = f2bf(v.y); u.z = f2bf(v.z); u.w = f2bf(v.w);
    *(ushort4*)&Xb[i] = u;
}

// in: [E][R][C] fp32  ->  out: [E][C][R] bf16
__global__ __launch_bounds__(256) void transpose_cvt_kernel(
    const float* __restrict__ in, unsigned short* __restrict__ out,
    int R, int C)
{
    __shared__ unsigned short tile[64][65];
    int e = blockIdx.z;
    const float* src = in + (size_t)e * R * C;
    unsigned short* dst = out + (size_t)e * R * C;
    int r0 = blockIdx.x * 64, c0 = blockIdx.y * 64;
    int tid = threadIdx.x;
    int rr = tid >> 2, cb = (tid & 3) * 16;
#pragma unroll
    for (int i = 0; i < 4; ++i) {
        float4 v = *(const float4*)&src[(size_t)(r0 + rr) * C + c0 + cb + i * 4];
        tile[rr][cb + i * 4 + 0] = f2bf(v.x);
        tile[rr][cb + i * 4 + 1] = f2bf(v.y);
        tile[rr][cb + i * 4 + 2] = f2bf(v.z);
        tile[rr][cb + i * 4 + 3] = f2bf(v.w);
    }
    __syncthreads();
#pragma unroll
    for (int i = 0; i < 4; ++i) {
        ushort4 u;
        u.x = tile[cb + i * 4 + 0][rr];
        u.y = tile[cb + i * 4 + 1][rr];
        u.z = tile[cb + i * 4 + 2][rr];
        u.w = tile[cb + i * 4 + 3][rr];
        *(ushort4*)&dst[(size_t)(c0 + rr) * R + r0 + cb + i * 4] = u;
    }
}

// ------------------------------------------------------------- MFMA GEMM ----
// LDS tiles: 128 rows x 32 bf16, row stride 40 ushorts (80 B, 16B-aligned,
// 2-way bank aliasing = free). A-frag: A[m=lane&15][k=quad*8+j]; B stored
// transposed so B-frag rows are k-contiguous. C/D: col=lane&15, row=quad*4+r.

__global__ __launch_bounds__(256) void gemm1_kernel(
    const unsigned short* __restrict__ Xb, const unsigned short* __restrict__ W1t,
    const float* __restrict__ b1, const int* __restrict__ cnt,
    const int* __restrict__ offs, const int* __restrict__ btok,
    unsigned short* __restrict__ H1)
{
    __shared__ __align__(16) unsigned short As[128 * 40];
    __shared__ __align__(16) unsigned short Bs[128 * 40];
    __shared__ int tok_s[128];

    int e = blockIdx.z, tt = blockIdx.x, ht = blockIdx.y;
    int cn = cnt[e];
    if (tt * 128 >= cn) return;
    int off_e = offs[e];
    int tid = threadIdx.x;

    if (tid < 128) {
        int lr = tt * 128 + tid;
        tok_s[tid] = (lr < cn) ? btok[off_e + lr] : 0;
    }
    __syncthreads();

    int wave = tid >> 6, lane = tid & 63;
    int mbase = (wave >> 1) * 64, nbase = (wave & 1) * 64;
    f32x4 acc[4][4];
#pragma unroll
    for (int mi = 0; mi < 4; ++mi)
#pragma unroll
        for (int ni = 0; ni < 4; ++ni)
            acc[mi][ni] = (f32x4){0.f, 0.f, 0.f, 0.f};

    int r_s = tid >> 2, c_s = (tid & 3) * 8;
    const unsigned short* Bsrc = W1t + ((size_t)e * HID + ht * 128) * DIM;
    int ka = (lane >> 4) * 8;

    for (int k0 = 0; k0 < DIM; k0 += 32) {
#pragma unroll
        for (int p = 0; p < 2; ++p) {
            int r = r_s + p * 64;
            uint4 va = *(const uint4*)&Xb[(size_t)tok_s[r] * DIM + k0 + c_s];
            *(uint4*)&As[r * 40 + c_s] = va;
            uint4 vb = *(const uint4*)&Bsrc[(size_t)r * DIM + k0 + c_s];
            *(uint4*)&Bs[r * 40 + c_s] = vb;
        }
        __syncthreads();
        short8 a[4], b[4];
#pragma unroll
        for (int i = 0; i < 4; ++i) {
            a[i] = *(const short8*)&As[(mbase + i * 16 + (lane & 15)) * 40 + ka];
            b[i] = *(const short8*)&Bs[(nbase + i * 16 + (lane & 15)) * 40 + ka];
        }
#pragma unroll
        for (int mi = 0; mi < 4; ++mi)
#pragma unroll
            for (int ni = 0; ni < 4; ++ni)
                acc[mi][ni] = __builtin_amdgcn_mfma_f32_16x16x32_bf16(
                    a[mi], b[ni], acc[mi][ni], 0, 0, 0);
        __syncthreads();
    }

    int quad = lane >> 4, lcol = lane & 15;
#pragma unroll
    for (int ni = 0; ni < 4; ++ni) {
        int h = ht * 128 + nbase + ni * 16 + lcol;
        float bv = b1[e * HID + h];
#pragma unroll
        for (int mi = 0; mi < 4; ++mi) {
            int rl = mbase + mi * 16 + quad * 4;
#pragma unroll
            for (int r = 0; r < 4; ++r) {
                int lrow = tt * 128 + rl + r;
                if (lrow < cn)
                    H1[(size_t)(off_e + lrow) * HID + h] = f2bf(acc[mi][ni][r] + bv);
            }
        }
    }
}

__global__ __launch_bounds__(256) void gemm2_kernel(
    const unsigned short* __restrict__ H1, const unsigned short* __restrict__ W2t,
    const float* __restrict__ b2, const int* __restrict__ cnt,
    const int* __restrict__ offs, const int* __restrict__ btok,
    const float* __restrict__ bwt, float* __restrict__ out)
{
    __shared__ __align__(16) unsigned short As[128 * 40];
    __shared__ __align__(16) unsigned short Bs[128 * 40];
    __shared__ int   tok_s[128];
    __shared__ float wt_s[128];

    int e = blockIdx.z, tt = blockIdx.x, dt = blockIdx.y;
    int cn = cnt[e];
    if (tt * 128 >= cn) return;
    int off_e = offs[e];
    int sb = off_e + tt * 128;
    int tid = threadIdx.x;

    if (tid < 128) {
        int lr = tt * 128 + tid;
        if (lr < cn) { tok_s[tid] = btok[off_e + lr]; wt_s[tid] = bwt[off_e + lr]; }
        else         { tok_s[tid] = 0;               wt_s[tid] = 0.f; }
    }
    __syncthreads();

    int wave = tid >> 6, lane = tid & 63;
    int mbase = (wave >> 1) * 64, nbase = (wave & 1) * 64;
    f32x4 acc[4][4];
#pragma unroll
    for (int mi = 0; mi < 4; ++mi)
#pragma unroll
        for (int ni = 0; ni < 4; ++ni)
            acc[mi][ni] = (f32x4){0.f, 0.f, 0.f, 0.f};

    int r_s = tid >> 2, c_s = (tid & 3) * 8;
    const unsigned short* Bsrc = W2t + ((size_t)e * DIM + dt * 128) * HID;
    int ka = (lane >> 4) * 8;

    for (int k0 = 0; k0 < HID; k0 += 32) {
#pragma unroll
        for (int p = 0; p < 2; ++p) {
            int r = r_s + p * 64;
            int sr = sb + r; if (sr > TOTSLOT - 1) sr = TOTSLOT - 1;
            uint4 va = *(const uint4*)&H1[(size_t)sr * HID + k0 + c_s];
            *(uint4*)&As[r * 40 + c_s] = va;
            uint4 vb = *(const uint4*)&Bsrc[(size_t)r * HID + k0 + c_s];
            *(uint4*)&Bs[r * 40 + c_s] = vb;
        }
        __syncthreads();
        short8 a[4], b[4];
#pragma unroll
        for (int i = 0; i < 4; ++i) {
            a[i] = *(const short8*)&As[(mbase + i * 16 + (lane & 15)) * 40 + ka];
            b[i] = *(const short8*)&Bs[(nbase + i * 16 + (lane & 15)) * 40 + ka];
        }
#pragma unroll
        for (int mi = 0; mi < 4; ++mi)
#pragma unroll
            for (int ni = 0; ni < 4; ++ni)
                acc[mi][ni] = __builtin_amdgcn_mfma_f32_16x16x32_bf16(
                    a[mi], b[ni], acc[mi][ni], 0, 0, 0);
        __syncthreads();
    }

    int quad = lane >> 4, lcol = lane & 15;
#pragma unroll
    for (int ni = 0; ni < 4; ++ni) {
        int d = dt * 128 + nbase + ni * 16 + lcol;
        float bv = b2[e * DIM + d];
#pragma unroll
        for (int mi = 0; mi < 4; ++mi) {
            int rl = mbase + mi * 16 + quad * 4;
#pragma unroll
            for (int r = 0; r < 4; ++r) {
                int lrow = rl + r;
                if (tt * 128 + lrow < cn) {
                    float w = wt_s[lrow];
                    atomicAdd(&out[(size_t)tok_s[lrow] * DIM + d],
                              w * (acc[mi][ni][r] + bv));
                }
            }
        }
    }
}

// ------------------------------------------------- round-1 fp32 fallback ----
#define TN 16
#define HC 256
#define NCHUNK (HID / HC)

__global__ __launch_bounds__(256) void gating_fb_kernel(
    const float* __restrict__ x, const float* __restrict__ Wg,
    const float* __restrict__ bg,
    int* __restrict__ cnt, int* __restrict__ btok, float* __restrict__ bwt,
    float* __restrict__ usage)
{
    int wave = threadIdx.x >> 6;
    int lane = threadIdx.x & 63;
    int n = blockIdx.x * 4 + wave;
    float acc[NEXP];
#pragma unroll
    for (int e = 0; e < NEXP; ++e) acc[e] = 0.f;
    for (int d = lane; d < DIM; d += 64) {
        float xv = x[n * DIM + d];
        float4 wa = *(const float4*)&Wg[d * NEXP];
        float4 wb = *(const float4*)&Wg[d * NEXP + 4];
        acc[0] += xv * wa.x; acc[1] += xv * wa.y;
        acc[2] += xv * wa.z; acc[3] += xv * wa.w;
        acc[4] += xv * wb.x; acc[5] += xv * wb.y;
        acc[6] += xv * wb.z; acc[7] += xv * wb.w;
    }
#pragma unroll
    for (int m = 32; m >= 1; m >>= 1)
#pragma unroll
        for (int e = 0; e < NEXP; ++e)
            acc[e] += __shfl_xor(acc[e], m, 64);
    if (lane == 0) {
        float l[NEXP];
#pragma unroll
        for (int e = 0; e < NEXP; ++e) l[e] = acc[e] + bg[e];
        int i0 = 0;
#pragma unroll
        for (int e = 1; e < NEXP; ++e) if (l[e] > l[i0]) i0 = e;
        int i1 = (i0 == 0) ? 1 : 0;
#pragma unroll
        for (int e = 0; e < NEXP; ++e)
            if (e != i0 && l[e] > l[i1]) i1 = e;
        float w0 = 1.f / (1.f + expf(l[i1] - l[i0]));
        float w1 = 1.f - w0;
        int p0 = atomicAdd(&cnt[i0], 1);
        btok[i0 * N_TOK + p0] = n; bwt[i0 * N_TOK + p0] = w0;
        int p1 = atomicAdd(&cnt[i1], 1);
        btok[i1 * N_TOK + p1] = n; bwt[i1 * N_TOK + p1] = w1;
        atomicAdd(&usage[i0], w0);
        atomicAdd(&usage[i1], w1);
    }
}

__global__ __launch_bounds__(256) void expert_fb_kernel(
    const float* __restrict__ x, const float* __restrict__ W1,
    const float* __restrict__ b1, const float* __restrict__ W2,
    const float* __restrict__ b2, const int* __restrict__ cnt,
    const int* __restrict__ btok, const float* __restrict__ bwt,
    float* __restrict__ out)
{
    __shared__ float xs[TN][DIM];
    __shared__ float h1s[TN][HC];
    __shared__ int   tok_s[TN];
    __shared__ float wt_s[TN];
    int e = blockIdx.x >> 8;
    int tile = blockIdx.x & 255;
    int cn = cnt[e];
    int n0 = tile * TN;
    if (n0 >= cn) return;
    int nt = min(TN, cn - n0);
    int tid = threadIdx.x;
    if (tid < TN) {
        if (tid < nt) { tok_s[tid] = btok[e * N_TOK + n0 + tid]; wt_s[tid] = bwt[e * N_TOK + n0 + tid]; }
        else          { tok_s[tid] = 0; wt_s[tid] = 0.f; }
    }
    __syncthreads();
    for (int idx = tid; idx < TN * DIM; idx += 256) {
        int t = idx >> 9, d = idx & 511;
        xs[t][d] = (t < nt) ? x[tok_s[t] * DIM + d] : 0.f;
    }
    const float* W1e = W1 + (size_t)e * DIM * HID;
    const float* W2e = W2 + (size_t)e * HID * DIM;
    int tg = tid >> 6, lane = tid & 63;
    float oacc[4][8];
    {
        float4 ba = *(const float4*)&b2[e * DIM + lane * 8];
        float4 bb = *(const float4*)&b2[e * DIM + lane * 8 + 4];
#pragma unroll
        for (int ti = 0; ti < 4; ++ti) {
            oacc[ti][0] = ba.x; oacc[ti][1] = ba.y; oacc[ti][2] = ba.z; oacc[ti][3] = ba.w;
            oacc[ti][4] = bb.x; oacc[ti][5] = bb.y; oacc[ti][6] = bb.z; oacc[ti][7] = bb.w;
        }
    }
    __syncthreads();
    for (int ch = 0; ch < NCHUNK; ++ch) {
        int h0 = ch * HC;
        float f[4][4];
        {
            float4 b1v = *(const float4*)&b1[e * HID + h0 + lane * 4];
#pragma unroll
            for (int ti = 0; ti < 4; ++ti) {
                f[ti][0] = b1v.x; f[ti][1] = b1v.y; f[ti][2] = b1v.z; f[ti][3] = b1v.w;
            }
        }
        for (int d = 0; d < DIM; ++d) {
            float4 w1v = *(const float4*)&W1e[(size_t)d * HID + h0 + lane * 4];
#pragma unroll
            for (int ti = 0; ti < 4; ++ti) {
                float xv = xs[tg + 4 * ti][d];
                f[ti][0] += xv * w1v.x; f[ti][1] += xv * w1v.y;
                f[ti][2] += xv * w1v.z; f[ti][3] += xv * w1v.w;
            }
        }
        __syncthreads();
#pragma unroll
        for (int ti = 0; ti < 4; ++ti)
            *(float4*)&h1s[tg + 4 * ti][lane * 4] = make_float4(f[ti][0], f[ti][1], f[ti][2], f[ti][3]);
        __syncthreads();
        for (int j = 0; j < HC; ++j) {
            const float* w2row = &W2e[(size_t)(h0 + j) * DIM + lane * 8];
            float4 wa = *(const float4*)w2row;
            float4 wb = *(const float4*)(w2row + 4);
#pragma unroll
            for (int ti = 0; ti < 4; ++ti) {
                float hv = h1s[tg + 4 * ti][j];
                oacc[ti][0] += hv * wa.x; oacc[ti][1] += hv * wa.y;
                oacc[ti][2] += hv * wa.z; oacc[ti][3] += hv * wa.w;
                oacc[ti][4] += hv * wb.x; oacc[ti][5] += hv * wb.y;
                oacc[ti][6] += hv * wb.z; oacc[ti][7] += hv * wb.w;
            }
        }
    }
#pragma unroll
    for (int ti = 0; ti < 4; ++ti) {
        int t = tg + 4 * ti;
        if (t < nt) {
            float w = wt_s[t];
            float* o = &out[(size_t)tok_s[t] * DIM + lane * 8];
#pragma unroll
            for (int c = 0; c < 8; ++c)
                atomicAdd(&o[c], w * oacc[ti][c]);
        }
    }
}

// ------------------------------------------------------------------ host ----
extern "C" void kernel_launch(void* const* d_in, const int* in_sizes, int n_in,
                              void* d_out, int out_size, void* d_ws, size_t ws_size,
                              hipStream_t stream) {
    const float* x  = (const float*)d_in[0];
    const float* Wg = (const float*)d_in[1];
    const float* bg = (const float*)d_in[2];
    const float* W1 = (const float*)d_in[3];
    const float* b1 = (const float*)d_in[4];
    const float* W2 = (const float*)d_in[5];
    const float* b2 = (const float*)d_in[6];

    float* out   = (float*)d_out;
    float* usage = out + (size_t)N_TOK * DIM;

    // ws layout (bf16 path)
    char* ws = (char*)d_ws;
    int*   cnt  = (int*)(ws + 0);
    int*   fill = (int*)(ws + 32);
    int*   offs = (int*)(ws + 64);
    int*   te   = (int*)(ws + 256);
    float* tw   = (float*)(ws + 33024);
    int*   btok = (int*)(ws + 65792);
    float* bwt  = (float*)(ws + 98560);
    unsigned short* Xb  = (unsigned short*)(ws + 131328);
    unsigned short* W1t = (unsigned short*)(ws + 4325632);
    unsigned short* W2t = (unsigned short*)(ws + 21102848);
    unsigned short* H1  = (unsigned short*)(ws + 37880064);
    const size_t WS_NEED = 71434496ULL;

    hipMemsetAsync(d_out, 0, (size_t)(N_TOK * DIM + NEXP) * sizeof(float), stream);

    if (ws_size >= WS_NEED) {
        hipMemsetAsync(cnt, 0, 32, stream);
        cvtx_kernel<<<N_TOK * DIM / 1024, 256, 0, stream>>>(x, Xb);
        transpose_cvt_kernel<<<dim3(DIM / 64, HID / 64, NEXP), 256, 0, stream>>>(W1, W1t, DIM, HID);
        transpose_cvt_kernel<<<dim3(HID / 64, DIM / 64, NEXP), 256, 0, stream>>>(W2, W2t, HID, DIM);
        gating_kernel<<<N_TOK / 4, 256, 0, stream>>>(x, Wg, bg, cnt, te, tw, usage);
        prefix_kernel<<<1, 64, 0, stream>>>(cnt, offs, fill);
        scatter_kernel<<<N_TOK / 256, 256, 0, stream>>>(te, tw, offs, fill, btok, bwt);
        gemm1_kernel<<<dim3(N_TOK / 128, HID / 128, NEXP), 256, 0, stream>>>(
            Xb, W1t, b1, cnt, offs, btok, H1);
        gemm2_kernel<<<dim3(N_TOK / 128, DIM / 128, NEXP), 256, 0, stream>>>(
            H1, W2t, b2, cnt, offs, btok, bwt, out);
    } else {
        // round-1 fp32 fallback (ws >= 256.3 KB, verified in round 1)
        int*   fcnt  = (int*)d_ws;
        int*   fbtok = (int*)((char*)d_ws + 256);
        float* fbwt  = (float*)((char*)d_ws + 256 + (size_t)NEXP * N_TOK * sizeof(int));
        hipMemsetAsync(d_ws, 0, 256, stream);
        gating_fb_kernel<<<N_TOK / 4, 256, 0, stream>>>(x, Wg, bg, fcnt, fbtok, fbwt, usage);
        expert_fb_kernel<<<NEXP * (N_TOK / TN), 256, 0, stream>>>(
            x, W1, b1, W2, b2, fcnt, fbtok, fbwt, out);
    }
}

// Round 3
// 378.575 us; speedup vs baseline: 3.1367x; 1.4777x over previous
//
#include <hip/hip_runtime.h>
#include <hip/hip_bf16.h>

// MoE: N=4096 tokens, D=512, H=2048, E=8 experts, top-2.
// Round 3: grid compaction. Round-2 grids were 75% dead blocks whose live
// pattern (lin%32 < 8) clustered work onto ~64 of 256 CUs (occupancy 5.9%,
// MfmaUtil 3.9%). Now a device-built tile table launches only live
// (expert, token-tile) pairs; gemm2 additionally split-K=2 (epilogue already
// atomic). Inner GEMM loops unchanged from the verified round-2 kernels.

#define N_TOK 4096
#define DIM   512
#define HID   2048
#define NEXP  8
#define TOTSLOT (2 * N_TOK)
#define MAXTILE 72   // sum ceil(cn_e/128) <= 64 + 7 = 71

typedef __attribute__((ext_vector_type(8))) short short8;
typedef __attribute__((ext_vector_type(4))) float f32x4;

static __device__ __forceinline__ unsigned short f2bf(float f) {
    __hip_bfloat16 b = __float2bfloat16(f);
    return *reinterpret_cast<unsigned short*>(&b);
}

// ---------------------------------------------------------------- gating ----
__global__ __launch_bounds__(256) void gating_kernel(
    const float* __restrict__ x, const float* __restrict__ Wg,
    const float* __restrict__ bg,
    int* __restrict__ cnt, int* __restrict__ te, float* __restrict__ tw,
    float* __restrict__ usage)
{
    int wave = threadIdx.x >> 6;
    int lane = threadIdx.x & 63;
    int n = blockIdx.x * 4 + wave;

    float acc[NEXP];
#pragma unroll
    for (int e = 0; e < NEXP; ++e) acc[e] = 0.f;

    for (int d = lane; d < DIM; d += 64) {
        float xv = x[n * DIM + d];
        float4 wa = *(const float4*)&Wg[d * NEXP];
        float4 wb = *(const float4*)&Wg[d * NEXP + 4];
        acc[0] += xv * wa.x; acc[1] += xv * wa.y;
        acc[2] += xv * wa.z; acc[3] += xv * wa.w;
        acc[4] += xv * wb.x; acc[5] += xv * wb.y;
        acc[6] += xv * wb.z; acc[7] += xv * wb.w;
    }
#pragma unroll
    for (int m = 32; m >= 1; m >>= 1) {
#pragma unroll
        for (int e = 0; e < NEXP; ++e)
            acc[e] += __shfl_xor(acc[e], m, 64);
    }
    if (lane == 0) {
        float l[NEXP];
#pragma unroll
        for (int e = 0; e < NEXP; ++e) l[e] = acc[e] + bg[e];
        int i0 = 0;
#pragma unroll
        for (int e = 1; e < NEXP; ++e) if (l[e] > l[i0]) i0 = e;
        int i1 = (i0 == 0) ? 1 : 0;
#pragma unroll
        for (int e = 0; e < NEXP; ++e)
            if (e != i0 && l[e] > l[i1]) i1 = e;
        float w0 = 1.f / (1.f + expf(l[i1] - l[i0]));
        float w1 = 1.f - w0;
        te[n * 2] = i0; te[n * 2 + 1] = i1;
        tw[n * 2] = w0; tw[n * 2 + 1] = w1;
        atomicAdd(&cnt[i0], 1);
        atomicAdd(&cnt[i1], 1);
        atomicAdd(&usage[i0], w0);
        atomicAdd(&usage[i1], w1);
    }
}

__global__ void prefix_kernel(const int* __restrict__ cnt,
                              int* __restrict__ offs, int* __restrict__ fill,
                              unsigned short* __restrict__ tile_tab,
                              int* __restrict__ ntile)
{
    if (threadIdx.x == 0) {
        int s = 0, nt = 0;
        for (int e = 0; e < NEXP; ++e) {
            offs[e] = s; s += cnt[e];
            int t = (cnt[e] + 127) >> 7;
            for (int i = 0; i < t; ++i)
                tile_tab[nt++] = (unsigned short)((e << 8) | i);
        }
        *ntile = nt;
        for (int i = nt; i < MAXTILE; ++i) tile_tab[i] = 0;
    }
    if (threadIdx.x < NEXP) fill[threadIdx.x] = 0;
}

__global__ __launch_bounds__(256) void scatter_kernel(
    const int* __restrict__ te, const float* __restrict__ tw,
    const int* __restrict__ offs, int* __restrict__ fill,
    int* __restrict__ btok, float* __restrict__ bwt)
{
    __shared__ int lcnt[NEXP];
    __shared__ int gbase[NEXP];
    int tid = threadIdx.x;
    if (tid < NEXP) lcnt[tid] = 0;
    __syncthreads();
    int n = blockIdx.x * 256 + tid;
    int e0 = te[n * 2], e1 = te[n * 2 + 1];
    int l0 = atomicAdd(&lcnt[e0], 1);
    int l1 = atomicAdd(&lcnt[e1], 1);
    __syncthreads();
    if (tid < NEXP) gbase[tid] = atomicAdd(&fill[tid], lcnt[tid]);
    __syncthreads();
    int s0 = offs[e0] + gbase[e0] + l0;
    int s1 = offs[e1] + gbase[e1] + l1;
    btok[s0] = n; bwt[s0] = tw[n * 2];
    btok[s1] = n; bwt[s1] = tw[n * 2 + 1];
}

// ----------------------------------------------------------- conversions ----
__global__ __launch_bounds__(256) void cvtx_kernel(
    const float* __restrict__ x, unsigned short* __restrict__ Xb)
{
    int i = (blockIdx.x * 256 + threadIdx.x) * 4;
    float4 v = *(const float4*)&x[i];
    ushort4 u;
    u.x = f2bf(v.x); u.y = f2bf(v.y); u.z = f2bf(v.z); u.w = f2bf(v.w);
    *(ushort4*)&Xb[i] = u;
}

// in: [E][R][C] fp32  ->  out: [E][C][R] bf16
__global__ __launch_bounds__(256) void transpose_cvt_kernel(
    const float* __restrict__ in, unsigned short* __restrict__ out,
    int R, int C)
{
    __shared__ unsigned short tile[64][65];
    int e = blockIdx.z;
    const float* src = in + (size_t)e * R * C;
    unsigned short* dst = out + (size_t)e * R * C;
    int r0 = blockIdx.x * 64, c0 = blockIdx.y * 64;
    int tid = threadIdx.x;
    int rr = tid >> 2, cb = (tid & 3) * 16;
#pragma unroll
    for (int i = 0; i < 4; ++i) {
        float4 v = *(const float4*)&src[(size_t)(r0 + rr) * C + c0 + cb + i * 4];
        tile[rr][cb + i * 4 + 0] = f2bf(v.x);
        tile[rr][cb + i * 4 + 1] = f2bf(v.y);
        tile[rr][cb + i * 4 + 2] = f2bf(v.z);
        tile[rr][cb + i * 4 + 3] = f2bf(v.w);
    }
    __syncthreads();
#pragma unroll
    for (int i = 0; i < 4; ++i) {
        ushort4 u;
        u.x = tile[cb + i * 4 + 0][rr];
        u.y = tile[cb + i * 4 + 1][rr];
        u.z = tile[cb + i * 4 + 2][rr];
        u.w = tile[cb + i * 4 + 3][rr];
        *(ushort4*)&dst[(size_t)(c0 + rr) * R + r0 + cb + i * 4] = u;
    }
}

// ------------------------------------------------------------- MFMA GEMM ----
// LDS tiles: 128 rows x 32 bf16, row stride 40 ushorts. A-frag:
// A[m=lane&15][k=quad*8+j]; B stored transposed (rows k-contiguous).
// C/D: col=lane&15, row=quad*4+r.

__global__ __launch_bounds__(256) void gemm1_kernel(
    const unsigned short* __restrict__ Xb, const unsigned short* __restrict__ W1t,
    const float* __restrict__ b1, const int* __restrict__ cnt,
    const int* __restrict__ offs, const int* __restrict__ btok,
    const unsigned short* __restrict__ tile_tab, const int* __restrict__ ntile,
    unsigned short* __restrict__ H1)
{
    __shared__ __align__(16) unsigned short As[128 * 40];
    __shared__ __align__(16) unsigned short Bs[128 * 40];
    __shared__ int tok_s[128];

    int ti = blockIdx.x;
    if (ti >= *ntile) return;
    unsigned short tv = tile_tab[ti];
    int e = tv >> 8, tt = tv & 255, ht = blockIdx.y;
    int cn = cnt[e];
    int off_e = offs[e];
    int tid = threadIdx.x;

    if (tid < 128) {
        int lr = tt * 128 + tid;
        tok_s[tid] = (lr < cn) ? btok[off_e + lr] : 0;
    }
    __syncthreads();

    int wave = tid >> 6, lane = tid & 63;
    int mbase = (wave >> 1) * 64, nbase = (wave & 1) * 64;
    f32x4 acc[4][4];
#pragma unroll
    for (int mi = 0; mi < 4; ++mi)
#pragma unroll
        for (int ni = 0; ni < 4; ++ni)
            acc[mi][ni] = (f32x4){0.f, 0.f, 0.f, 0.f};

    int r_s = tid >> 2, c_s = (tid & 3) * 8;
    const unsigned short* Bsrc = W1t + ((size_t)e * HID + ht * 128) * DIM;
    int ka = (lane >> 4) * 8;

    for (int k0 = 0; k0 < DIM; k0 += 32) {
#pragma unroll
        for (int p = 0; p < 2; ++p) {
            int r = r_s + p * 64;
            uint4 va = *(const uint4*)&Xb[(size_t)tok_s[r] * DIM + k0 + c_s];
            *(uint4*)&As[r * 40 + c_s] = va;
            uint4 vb = *(const uint4*)&Bsrc[(size_t)r * DIM + k0 + c_s];
            *(uint4*)&Bs[r * 40 + c_s] = vb;
        }
        __syncthreads();
        short8 a[4], b[4];
#pragma unroll
        for (int i = 0; i < 4; ++i) {
            a[i] = *(const short8*)&As[(mbase + i * 16 + (lane & 15)) * 40 + ka];
            b[i] = *(const short8*)&Bs[(nbase + i * 16 + (lane & 15)) * 40 + ka];
        }
#pragma unroll
        for (int mi = 0; mi < 4; ++mi)
#pragma unroll
            for (int ni = 0; ni < 4; ++ni)
                acc[mi][ni] = __builtin_amdgcn_mfma_f32_16x16x32_bf16(
                    a[mi], b[ni], acc[mi][ni], 0, 0, 0);
        __syncthreads();
    }

    int quad = lane >> 4, lcol = lane & 15;
#pragma unroll
    for (int ni = 0; ni < 4; ++ni) {
        int h = ht * 128 + nbase + ni * 16 + lcol;
        float bv = b1[e * HID + h];
#pragma unroll
        for (int mi = 0; mi < 4; ++mi) {
            int rl = mbase + mi * 16 + quad * 4;
#pragma unroll
            for (int r = 0; r < 4; ++r) {
                int lrow = tt * 128 + rl + r;
                if (lrow < cn)
                    H1[(size_t)(off_e + lrow) * HID + h] = f2bf(acc[mi][ni][r] + bv);
            }
        }
    }
}

#define KSPLIT 2
#define KCH (HID / KSPLIT)

__global__ __launch_bounds__(256) void gemm2_kernel(
    const unsigned short* __restrict__ H1, const unsigned short* __restrict__ W2t,
    const float* __restrict__ b2, const int* __restrict__ cnt,
    const int* __restrict__ offs, const int* __restrict__ btok,
    const float* __restrict__ bwt,
    const unsigned short* __restrict__ tile_tab, const int* __restrict__ ntile,
    float* __restrict__ out)
{
    __shared__ __align__(16) unsigned short As[128 * 40];
    __shared__ __align__(16) unsigned short Bs[128 * 40];
    __shared__ int   tok_s[128];
    __shared__ float wt_s[128];

    int ti = blockIdx.x;
    if (ti >= *ntile) return;
    unsigned short tv = tile_tab[ti];
    int e = tv >> 8, tt = tv & 255, dt = blockIdx.y, kz = blockIdx.z;
    int cn = cnt[e];
    int off_e = offs[e];
    int sb = off_e + tt * 128;
    int tid = threadIdx.x;

    if (tid < 128) {
        int lr = tt * 128 + tid;
        if (lr < cn) { tok_s[tid] = btok[off_e + lr]; wt_s[tid] = bwt[off_e + lr]; }
        else         { tok_s[tid] = 0;               wt_s[tid] = 0.f; }
    }
    __syncthreads();

    int wave = tid >> 6, lane = tid & 63;
    int mbase = (wave >> 1) * 64, nbase = (wave & 1) * 64;
    f32x4 acc[4][4];
#pragma unroll
    for (int mi = 0; mi < 4; ++mi)
#pragma unroll
        for (int ni = 0; ni < 4; ++ni)
            acc[mi][ni] = (f32x4){0.f, 0.f, 0.f, 0.f};

    int r_s = tid >> 2, c_s = (tid & 3) * 8;
    const unsigned short* Bsrc = W2t + ((size_t)e * DIM + dt * 128) * HID;
    int ka = (lane >> 4) * 8;

    for (int k0 = kz * KCH; k0 < (kz + 1) * KCH; k0 += 32) {
#pragma unroll
        for (int p = 0; p < 2; ++p) {
            int r = r_s + p * 64;
            int sr = sb + r; if (sr > TOTSLOT - 1) sr = TOTSLOT - 1;
            uint4 va = *(const uint4*)&H1[(size_t)sr * HID + k0 + c_s];
            *(uint4*)&As[r * 40 + c_s] = va;
            uint4 vb = *(const uint4*)&Bsrc[(size_t)r * HID + k0 + c_s];
            *(uint4*)&Bs[r * 40 + c_s] = vb;
        }
        __syncthreads();
        short8 a[4], b[4];
#pragma unroll
        for (int i = 0; i < 4; ++i) {
            a[i] = *(const short8*)&As[(mbase + i * 16 + (lane & 15)) * 40 + ka];
            b[i] = *(const short8*)&Bs[(nbase + i * 16 + (lane & 15)) * 40 + ka];
        }
#pragma unroll
        for (int mi = 0; mi < 4; ++mi)
#pragma unroll
            for (int ni = 0; ni < 4; ++ni)
                acc[mi][ni] = __builtin_amdgcn_mfma_f32_16x16x32_bf16(
                    a[mi], b[ni], acc[mi][ni], 0, 0, 0);
        __syncthreads();
    }

    int quad = lane >> 4, lcol = lane & 15;
#pragma unroll
    for (int ni = 0; ni < 4; ++ni) {
        int d = dt * 128 + nbase + ni * 16 + lcol;
        float bv = (kz == 0) ? b2[e * DIM + d] : 0.f;
#pragma unroll
        for (int mi = 0; mi < 4; ++mi) {
            int rl = mbase + mi * 16 + quad * 4;
#pragma unroll
            for (int r = 0; r < 4; ++r) {
                int lrow = rl + r;
                if (tt * 128 + lrow < cn) {
                    float w = wt_s[lrow];
                    atomicAdd(&out[(size_t)tok_s[lrow] * DIM + d],
                              w * (acc[mi][ni][r] + bv));
                }
            }
        }
    }
}

// ------------------------------------------------- round-1 fp32 fallback ----
#define TN 16
#define HC 256
#define NCHUNK (HID / HC)

__global__ __launch_bounds__(256) void gating_fb_kernel(
    const float* __restrict__ x, const float* __restrict__ Wg,
    const float* __restrict__ bg,
    int* __restrict__ cnt, int* __restrict__ btok, float* __restrict__ bwt,
    float* __restrict__ usage)
{
    int wave = threadIdx.x >> 6;
    int lane = threadIdx.x & 63;
    int n = blockIdx.x * 4 + wave;
    float acc[NEXP];
#pragma unroll
    for (int e = 0; e < NEXP; ++e) acc[e] = 0.f;
    for (int d = lane; d < DIM; d += 64) {
        float xv = x[n * DIM + d];
        float4 wa = *(const float4*)&Wg[d * NEXP];
        float4 wb = *(const float4*)&Wg[d * NEXP + 4];
        acc[0] += xv * wa.x; acc[1] += xv * wa.y;
        acc[2] += xv * wa.z; acc[3] += xv * wa.w;
        acc[4] += xv * wb.x; acc[5] += xv * wb.y;
        acc[6] += xv * wb.z; acc[7] += xv * wb.w;
    }
#pragma unroll
    for (int m = 32; m >= 1; m >>= 1)
#pragma unroll
        for (int e = 0; e < NEXP; ++e)
            acc[e] += __shfl_xor(acc[e], m, 64);
    if (lane == 0) {
        float l[NEXP];
#pragma unroll
        for (int e = 0; e < NEXP; ++e) l[e] = acc[e] + bg[e];
        int i0 = 0;
#pragma unroll
        for (int e = 1; e < NEXP; ++e) if (l[e] > l[i0]) i0 = e;
        int i1 = (i0 == 0) ? 1 : 0;
#pragma unroll
        for (int e = 0; e < NEXP; ++e)
            if (e != i0 && l[e] > l[i1]) i1 = e;
        float w0 = 1.f / (1.f + expf(l[i1] - l[i0]));
        float w1 = 1.f - w0;
        int p0 = atomicAdd(&cnt[i0], 1);
        btok[i0 * N_TOK + p0] = n; bwt[i0 * N_TOK + p0] = w0;
        int p1 = atomicAdd(&cnt[i1], 1);
        btok[i1 * N_TOK + p1] = n; bwt[i1 * N_TOK + p1] = w1;
        atomicAdd(&usage[i0], w0);
        atomicAdd(&usage[i1], w1);
    }
}

__global__ __launch_bounds__(256) void expert_fb_kernel(
    const float* __restrict__ x, const float* __restrict__ W1,
    const float* __restrict__ b1, const float* __restrict__ W2,
    const float* __restrict__ b2, const int* __restrict__ cnt,
    const int* __restrict__ btok, const float* __restrict__ bwt,
    float* __restrict__ out)
{
    __shared__ float xs[TN][DIM];
    __shared__ float h1s[TN][HC];
    __shared__ int   tok_s[TN];
    __shared__ float wt_s[TN];
    int e = blockIdx.x >> 8;
    int tile = blockIdx.x & 255;
    int cn = cnt[e];
    int n0 = tile * TN;
    if (n0 >= cn) return;
    int nt = min(TN, cn - n0);
    int tid = threadIdx.x;
    if (tid < TN) {
        if (tid < nt) { tok_s[tid] = btok[e * N_TOK + n0 + tid]; wt_s[tid] = bwt[e * N_TOK + n0 + tid]; }
        else          { tok_s[tid] = 0; wt_s[tid] = 0.f; }
    }
    __syncthreads();
    for (int idx = tid; idx < TN * DIM; idx += 256) {
        int t = idx >> 9, d = idx & 511;
        xs[t][d] = (t < nt) ? x[tok_s[t] * DIM + d] : 0.f;
    }
    const float* W1e = W1 + (size_t)e * DIM * HID;
    const float* W2e = W2 + (size_t)e * HID * DIM;
    int tg = tid >> 6, lane = tid & 63;
    float oacc[4][8];
    {
        float4 ba = *(const float4*)&b2[e * DIM + lane * 8];
        float4 bb = *(const float4*)&b2[e * DIM + lane * 8 + 4];
#pragma unroll
        for (int ti = 0; ti < 4; ++ti) {
            oacc[ti][0] = ba.x; oacc[ti][1] = ba.y; oacc[ti][2] = ba.z; oacc[ti][3] = ba.w;
            oacc[ti][4] = bb.x; oacc[ti][5] = bb.y; oacc[ti][6] = bb.z; oacc[ti][7] = bb.w;
        }
    }
    __syncthreads();
    for (int ch = 0; ch < NCHUNK; ++ch) {
        int h0 = ch * HC;
        float f[4][4];
        {
            float4 b1v = *(const float4*)&b1[e * HID + h0 + lane * 4];
#pragma unroll
            for (int ti = 0; ti < 4; ++ti) {
                f[ti][0] = b1v.x; f[ti][1] = b1v.y; f[ti][2] = b1v.z; f[ti][3] = b1v.w;
            }
        }
        for (int d = 0; d < DIM; ++d) {
            float4 w1v = *(const float4*)&W1e[(size_t)d * HID + h0 + lane * 4];
#pragma unroll
            for (int ti = 0; ti < 4; ++ti) {
                float xv = xs[tg + 4 * ti][d];
                f[ti][0] += xv * w1v.x; f[ti][1] += xv * w1v.y;
                f[ti][2] += xv * w1v.z; f[ti][3] += xv * w1v.w;
            }
        }
        __syncthreads();
#pragma unroll
        for (int ti = 0; ti < 4; ++ti)
            *(float4*)&h1s[tg + 4 * ti][lane * 4] = make_float4(f[ti][0], f[ti][1], f[ti][2], f[ti][3]);
        __syncthreads();
        for (int j = 0; j < HC; ++j) {
            const float* w2row = &W2e[(size_t)(h0 + j) * DIM + lane * 8];
            float4 wa = *(const float4*)w2row;
            float4 wb = *(const float4*)(w2row + 4);
#pragma unroll
            for (int ti = 0; ti < 4; ++ti) {
                float hv = h1s[tg + 4 * ti][j];
                oacc[ti][0] += hv * wa.x; oacc[ti][1] += hv * wa.y;
                oacc[ti][2] += hv * wa.z; oacc[ti][3] += hv * wa.w;
                oacc[ti][4] += hv * wb.x; oacc[ti][5] += hv * wb.y;
                oacc[ti][6] += hv * wb.z; oacc[ti][7] += hv * wb.w;
            }
        }
    }
#pragma unroll
    for (int ti = 0; ti < 4; ++ti) {
        int t = tg + 4 * ti;
        if (t < nt) {
            float w = wt_s[t];
            float* o = &out[(size_t)tok_s[t] * DIM + lane * 8];
#pragma unroll
            for (int c = 0; c < 8; ++c)
                atomicAdd(&o[c], w * oacc[ti][c]);
        }
    }
}

// ------------------------------------------------------------------ host ----
extern "C" void kernel_launch(void* const* d_in, const int* in_sizes, int n_in,
                              void* d_out, int out_size, void* d_ws, size_t ws_size,
                              hipStream_t stream) {
    const float* x  = (const float*)d_in[0];
    const float* Wg = (const float*)d_in[1];
    const float* bg = (const float*)d_in[2];
    const float* W1 = (const float*)d_in[3];
    const float* b1 = (const float*)d_in[4];
    const float* W2 = (const float*)d_in[5];
    const float* b2 = (const float*)d_in[6];

    float* out   = (float*)d_out;
    float* usage = out + (size_t)N_TOK * DIM;

    // ws layout (bf16 path) — byte-identical footprint to round 2; tile table
    // packed into the 96..256 hole.
    char* ws = (char*)d_ws;
    int*   cnt  = (int*)(ws + 0);     // 8 ints
    int*   fill = (int*)(ws + 32);    // 8 ints
    int*   offs = (int*)(ws + 64);    // 8 ints
    unsigned short* tile_tab = (unsigned short*)(ws + 96);  // 72 ushorts -> 240
    int*   ntile = (int*)(ws + 240);
    int*   te   = (int*)(ws + 256);
    float* tw   = (float*)(ws + 33024);
    int*   btok = (int*)(ws + 65792);
    float* bwt  = (float*)(ws + 98560);
    unsigned short* Xb  = (unsigned short*)(ws + 131328);
    unsigned short* W1t = (unsigned short*)(ws + 4325632);
    unsigned short* W2t = (unsigned short*)(ws + 21102848);
    unsigned short* H1  = (unsigned short*)(ws + 37880064);
    const size_t WS_NEED = 71434496ULL;

    hipMemsetAsync(d_out, 0, (size_t)(N_TOK * DIM + NEXP) * sizeof(float), stream);

    if (ws_size >= WS_NEED) {
        hipMemsetAsync(cnt, 0, 32, stream);
        cvtx_kernel<<<N_TOK * DIM / 1024, 256, 0, stream>>>(x, Xb);
        transpose_cvt_kernel<<<dim3(DIM / 64, HID / 64, NEXP), 256, 0, stream>>>(W1, W1t, DIM, HID);
        transpose_cvt_kernel<<<dim3(HID / 64, DIM / 64, NEXP), 256, 0, stream>>>(W2, W2t, HID, DIM);
        gating_kernel<<<N_TOK / 4, 256, 0, stream>>>(x, Wg, bg, cnt, te, tw, usage);
        prefix_kernel<<<1, 64, 0, stream>>>(cnt, offs, fill, tile_tab, ntile);
        scatter_kernel<<<N_TOK / 256, 256, 0, stream>>>(te, tw, offs, fill, btok, bwt);
        gemm1_kernel<<<dim3(MAXTILE, HID / 128), 256, 0, stream>>>(
            Xb, W1t, b1, cnt, offs, btok, tile_tab, ntile, H1);
        gemm2_kernel<<<dim3(MAXTILE, DIM / 128, KSPLIT), 256, 0, stream>>>(
            H1, W2t, b2, cnt, offs, btok, bwt, tile_tab, ntile, out);
    } else {
        // round-1 fp32 fallback (verified)
        int*   fcnt  = (int*)d_ws;
        int*   fbtok = (int*)((char*)d_ws + 256);
        float* fbwt  = (float*)((char*)d_ws + 256 + (size_t)NEXP * N_TOK * sizeof(int));
        hipMemsetAsync(d_ws, 0, 256, stream);
        gating_fb_kernel<<<N_TOK / 4, 256, 0, stream>>>(x, Wg, bg, fcnt, fbtok, fbwt, usage);
        expert_fb_kernel<<<NEXP * (N_TOK / TN), 256, 0, stream>>>(
            x, W1, b1, W2, b2, fcnt, fbtok, fbwt, out);
    }
}

// Round 4
// 305.872 us; speedup vs baseline: 3.8823x; 1.2377x over previous
//
#include <hip/hip_runtime.h>
#include <hip/hip_bf16.h>

// MoE: N=4096 tokens, D=512, H=2048, E=8 experts, top-2.
// Round 4: gating atomic aggregation. Round-3 profile showed gating at 112 us
// with VALU 2.3% / HBM 0.5% — 16384 device-scope atomicAdds on two cache
// lines (cnt[8], usage[8]) serialized at ~7 ns each across XCDs. Now 64
// blocks x 64 tokens aggregate counts/usage in LDS, then 8 global atomics
// per block per array (16384 -> 1024 global RMWs). GEMM path unchanged
// (verified rounds 2-3).

#define N_TOK 4096
#define DIM   512
#define HID   2048
#define NEXP  8
#define TOTSLOT (2 * N_TOK)
#define MAXTILE 72   // sum ceil(cn_e/128) <= 64 + 7 = 71

typedef __attribute__((ext_vector_type(8))) short short8;
typedef __attribute__((ext_vector_type(4))) float f32x4;

static __device__ __forceinline__ unsigned short f2bf(float f) {
    __hip_bfloat16 b = __float2bfloat16(f);
    return *reinterpret_cast<unsigned short*>(&b);
}

// ---------------------------------------------------------------- gating ----
// 64 blocks x 64 tokens; wave w handles tokens [w*16, w*16+16) of its block.
__global__ __launch_bounds__(256) void gating_kernel(
    const float* __restrict__ x, const float* __restrict__ Wg,
    const float* __restrict__ bg,
    int* __restrict__ cnt, int* __restrict__ te, float* __restrict__ tw,
    float* __restrict__ usage)
{
    __shared__ int   lcnt[NEXP];
    __shared__ float lus[NEXP];
    int tid = threadIdx.x;
    if (tid < NEXP) { lcnt[tid] = 0; lus[tid] = 0.f; }
    __syncthreads();

    int wave = tid >> 6;
    int lane = tid & 63;

    for (int t = 0; t < 16; ++t) {
        int n = blockIdx.x * 64 + wave * 16 + t;

        float acc[NEXP];
#pragma unroll
        for (int e = 0; e < NEXP; ++e) acc[e] = 0.f;

#pragma unroll
        for (int it = 0; it < DIM / 64; ++it) {
            int d = it * 64 + lane;
            float xv = x[n * DIM + d];
            float4 wa = *(const float4*)&Wg[d * NEXP];
            float4 wb = *(const float4*)&Wg[d * NEXP + 4];
            acc[0] += xv * wa.x; acc[1] += xv * wa.y;
            acc[2] += xv * wa.z; acc[3] += xv * wa.w;
            acc[4] += xv * wb.x; acc[5] += xv * wb.y;
            acc[6] += xv * wb.z; acc[7] += xv * wb.w;
        }
#pragma unroll
        for (int m = 32; m >= 1; m >>= 1) {
#pragma unroll
            for (int e = 0; e < NEXP; ++e)
                acc[e] += __shfl_xor(acc[e], m, 64);
        }
        if (lane == 0) {
            float l[NEXP];
#pragma unroll
            for (int e = 0; e < NEXP; ++e) l[e] = acc[e] + bg[e];
            int i0 = 0;
#pragma unroll
            for (int e = 1; e < NEXP; ++e) if (l[e] > l[i0]) i0 = e;
            int i1 = (i0 == 0) ? 1 : 0;
#pragma unroll
            for (int e = 0; e < NEXP; ++e)
                if (e != i0 && l[e] > l[i1]) i1 = e;
            float w0 = 1.f / (1.f + expf(l[i1] - l[i0]));
            float w1 = 1.f - w0;
            te[n * 2] = i0; te[n * 2 + 1] = i1;
            tw[n * 2] = w0; tw[n * 2 + 1] = w1;
            atomicAdd(&lcnt[i0], 1);
            atomicAdd(&lcnt[i1], 1);
            atomicAdd(&lus[i0], w0);
            atomicAdd(&lus[i1], w1);
        }
    }
    __syncthreads();
    if (tid < NEXP) {
        if (lcnt[tid]) atomicAdd(&cnt[tid], lcnt[tid]);
        if (lus[tid] != 0.f) atomicAdd(&usage[tid], lus[tid]);
    }
}

__global__ void prefix_kernel(const int* __restrict__ cnt,
                              int* __restrict__ offs, int* __restrict__ fill,
                              unsigned short* __restrict__ tile_tab,
                              int* __restrict__ ntile)
{
    if (threadIdx.x == 0) {
        int s = 0, nt = 0;
        for (int e = 0; e < NEXP; ++e) {
            offs[e] = s; s += cnt[e];
            int t = (cnt[e] + 127) >> 7;
            for (int i = 0; i < t; ++i)
                tile_tab[nt++] = (unsigned short)((e << 8) | i);
        }
        *ntile = nt;
        for (int i = nt; i < MAXTILE; ++i) tile_tab[i] = 0;
    }
    if (threadIdx.x < NEXP) fill[threadIdx.x] = 0;
}

__global__ __launch_bounds__(256) void scatter_kernel(
    const int* __restrict__ te, const float* __restrict__ tw,
    const int* __restrict__ offs, int* __restrict__ fill,
    int* __restrict__ btok, float* __restrict__ bwt)
{
    __shared__ int lcnt[NEXP];
    __shared__ int gbase[NEXP];
    int tid = threadIdx.x;
    if (tid < NEXP) lcnt[tid] = 0;
    __syncthreads();
    int n = blockIdx.x * 256 + tid;
    int e0 = te[n * 2], e1 = te[n * 2 + 1];
    int l0 = atomicAdd(&lcnt[e0], 1);
    int l1 = atomicAdd(&lcnt[e1], 1);
    __syncthreads();
    if (tid < NEXP) gbase[tid] = atomicAdd(&fill[tid], lcnt[tid]);
    __syncthreads();
    int s0 = offs[e0] + gbase[e0] + l0;
    int s1 = offs[e1] + gbase[e1] + l1;
    btok[s0] = n; bwt[s0] = tw[n * 2];
    btok[s1] = n; bwt[s1] = tw[n * 2 + 1];
}

// ----------------------------------------------------------- conversions ----
__global__ __launch_bounds__(256) void cvtx_kernel(
    const float* __restrict__ x, unsigned short* __restrict__ Xb)
{
    int i = (blockIdx.x * 256 + threadIdx.x) * 4;
    float4 v = *(const float4*)&x[i];
    ushort4 u;
    u.x = f2bf(v.x); u.y = f2bf(v.y); u.z = f2bf(v.z); u.w = f2bf(v.w);
    *(ushort4*)&Xb[i] = u;
}

// in: [E][R][C] fp32  ->  out: [E][C][R] bf16
__global__ __launch_bounds__(256) void transpose_cvt_kernel(
    const float* __restrict__ in, unsigned short* __restrict__ out,
    int R, int C)
{
    __shared__ unsigned short tile[64][65];
    int e = blockIdx.z;
    const float* src = in + (size_t)e * R * C;
    unsigned short* dst = out + (size_t)e * R * C;
    int r0 = blockIdx.x * 64, c0 = blockIdx.y * 64;
    int tid = threadIdx.x;
    int rr = tid >> 2, cb = (tid & 3) * 16;
#pragma unroll
    for (int i = 0; i < 4; ++i) {
        float4 v = *(const float4*)&src[(size_t)(r0 + rr) * C + c0 + cb + i * 4];
        tile[rr][cb + i * 4 + 0] = f2bf(v.x);
        tile[rr][cb + i * 4 + 1] = f2bf(v.y);
        tile[rr][cb + i * 4 + 2] = f2bf(v.z);
        tile[rr][cb + i * 4 + 3] = f2bf(v.w);
    }
    __syncthreads();
#pragma unroll
    for (int i = 0; i < 4; ++i) {
        ushort4 u;
        u.x = tile[cb + i * 4 + 0][rr];
        u.y = tile[cb + i * 4 + 1][rr];
        u.z = tile[cb + i * 4 + 2][rr];
        u.w = tile[cb + i * 4 + 3][rr];
        *(ushort4*)&dst[(size_t)(c0 + rr) * R + r0 + cb + i * 4] = u;
    }
}

// ------------------------------------------------------------- MFMA GEMM ----
// LDS tiles: 128 rows x 32 bf16, row stride 40 ushorts. A-frag:
// A[m=lane&15][k=quad*8+j]; B stored transposed (rows k-contiguous).
// C/D: col=lane&15, row=quad*4+r.

__global__ __launch_bounds__(256) void gemm1_kernel(
    const unsigned short* __restrict__ Xb, const unsigned short* __restrict__ W1t,
    const float* __restrict__ b1, const int* __restrict__ cnt,
    const int* __restrict__ offs, const int* __restrict__ btok,
    const unsigned short* __restrict__ tile_tab, const int* __restrict__ ntile,
    unsigned short* __restrict__ H1)
{
    __shared__ __align__(16) unsigned short As[128 * 40];
    __shared__ __align__(16) unsigned short Bs[128 * 40];
    __shared__ int tok_s[128];

    int ti = blockIdx.x;
    if (ti >= *ntile) return;
    unsigned short tv = tile_tab[ti];
    int e = tv >> 8, tt = tv & 255, ht = blockIdx.y;
    int cn = cnt[e];
    int off_e = offs[e];
    int tid = threadIdx.x;

    if (tid < 128) {
        int lr = tt * 128 + tid;
        tok_s[tid] = (lr < cn) ? btok[off_e + lr] : 0;
    }
    __syncthreads();

    int wave = tid >> 6, lane = tid & 63;
    int mbase = (wave >> 1) * 64, nbase = (wave & 1) * 64;
    f32x4 acc[4][4];
#pragma unroll
    for (int mi = 0; mi < 4; ++mi)
#pragma unroll
        for (int ni = 0; ni < 4; ++ni)
            acc[mi][ni] = (f32x4){0.f, 0.f, 0.f, 0.f};

    int r_s = tid >> 2, c_s = (tid & 3) * 8;
    const unsigned short* Bsrc = W1t + ((size_t)e * HID + ht * 128) * DIM;
    int ka = (lane >> 4) * 8;

    for (int k0 = 0; k0 < DIM; k0 += 32) {
#pragma unroll
        for (int p = 0; p < 2; ++p) {
            int r = r_s + p * 64;
            uint4 va = *(const uint4*)&Xb[(size_t)tok_s[r] * DIM + k0 + c_s];
            *(uint4*)&As[r * 40 + c_s] = va;
            uint4 vb = *(const uint4*)&Bsrc[(size_t)r * DIM + k0 + c_s];
            *(uint4*)&Bs[r * 40 + c_s] = vb;
        }
        __syncthreads();
        short8 a[4], b[4];
#pragma unroll
        for (int i = 0; i < 4; ++i) {
            a[i] = *(const short8*)&As[(mbase + i * 16 + (lane & 15)) * 40 + ka];
            b[i] = *(const short8*)&Bs[(nbase + i * 16 + (lane & 15)) * 40 + ka];
        }
#pragma unroll
        for (int mi = 0; mi < 4; ++mi)
#pragma unroll
            for (int ni = 0; ni < 4; ++ni)
                acc[mi][ni] = __builtin_amdgcn_mfma_f32_16x16x32_bf16(
                    a[mi], b[ni], acc[mi][ni], 0, 0, 0);
        __syncthreads();
    }

    int quad = lane >> 4, lcol = lane & 15;
#pragma unroll
    for (int ni = 0; ni < 4; ++ni) {
        int h = ht * 128 + nbase + ni * 16 + lcol;
        float bv = b1[e * HID + h];
#pragma unroll
        for (int mi = 0; mi < 4; ++mi) {
            int rl = mbase + mi * 16 + quad * 4;
#pragma unroll
            for (int r = 0; r < 4; ++r) {
                int lrow = tt * 128 + rl + r;
                if (lrow < cn)
                    H1[(size_t)(off_e + lrow) * HID + h] = f2bf(acc[mi][ni][r] + bv);
            }
        }
    }
}

#define KSPLIT 2
#define KCH (HID / KSPLIT)

__global__ __launch_bounds__(256) void gemm2_kernel(
    const unsigned short* __restrict__ H1, const unsigned short* __restrict__ W2t,
    const float* __restrict__ b2, const int* __restrict__ cnt,
    const int* __restrict__ offs, const int* __restrict__ btok,
    const float* __restrict__ bwt,
    const unsigned short* __restrict__ tile_tab, const int* __restrict__ ntile,
    float* __restrict__ out)
{
    __shared__ __align__(16) unsigned short As[128 * 40];
    __shared__ __align__(16) unsigned short Bs[128 * 40];
    __shared__ int   tok_s[128];
    __shared__ float wt_s[128];

    int ti = blockIdx.x;
    if (ti >= *ntile) return;
    unsigned short tv = tile_tab[ti];
    int e = tv >> 8, tt = tv & 255, dt = blockIdx.y, kz = blockIdx.z;
    int cn = cnt[e];
    int off_e = offs[e];
    int sb = off_e + tt * 128;
    int tid = threadIdx.x;

    if (tid < 128) {
        int lr = tt * 128 + tid;
        if (lr < cn) { tok_s[tid] = btok[off_e + lr]; wt_s[tid] = bwt[off_e + lr]; }
        else         { tok_s[tid] = 0;               wt_s[tid] = 0.f; }
    }
    __syncthreads();

    int wave = tid >> 6, lane = tid & 63;
    int mbase = (wave >> 1) * 64, nbase = (wave & 1) * 64;
    f32x4 acc[4][4];
#pragma unroll
    for (int mi = 0; mi < 4; ++mi)
#pragma unroll
        for (int ni = 0; ni < 4; ++ni)
            acc[mi][ni] = (f32x4){0.f, 0.f, 0.f, 0.f};

    int r_s = tid >> 2, c_s = (tid & 3) * 8;
    const unsigned short* Bsrc = W2t + ((size_t)e * DIM + dt * 128) * HID;
    int ka = (lane >> 4) * 8;

    for (int k0 = kz * KCH; k0 < (kz + 1) * KCH; k0 += 32) {
#pragma unroll
        for (int p = 0; p < 2; ++p) {
            int r = r_s + p * 64;
            int sr = sb + r; if (sr > TOTSLOT - 1) sr = TOTSLOT - 1;
            uint4 va = *(const uint4*)&H1[(size_t)sr * HID + k0 + c_s];
            *(uint4*)&As[r * 40 + c_s] = va;
            uint4 vb = *(const uint4*)&Bsrc[(size_t)r * HID + k0 + c_s];
            *(uint4*)&Bs[r * 40 + c_s] = vb;
        }
        __syncthreads();
        short8 a[4], b[4];
#pragma unroll
        for (int i = 0; i < 4; ++i) {
            a[i] = *(const short8*)&As[(mbase + i * 16 + (lane & 15)) * 40 + ka];
            b[i] = *(const short8*)&Bs[(nbase + i * 16 + (lane & 15)) * 40 + ka];
        }
#pragma unroll
        for (int mi = 0; mi < 4; ++mi)
#pragma unroll
            for (int ni = 0; ni < 4; ++ni)
                acc[mi][ni] = __builtin_amdgcn_mfma_f32_16x16x32_bf16(
                    a[mi], b[ni], acc[mi][ni], 0, 0, 0);
        __syncthreads();
    }

    int quad = lane >> 4, lcol = lane & 15;
#pragma unroll
    for (int ni = 0; ni < 4; ++ni) {
        int d = dt * 128 + nbase + ni * 16 + lcol;
        float bv = (kz == 0) ? b2[e * DIM + d] : 0.f;
#pragma unroll
        for (int mi = 0; mi < 4; ++mi) {
            int rl = mbase + mi * 16 + quad * 4;
#pragma unroll
            for (int r = 0; r < 4; ++r) {
                int lrow = rl + r;
                if (tt * 128 + lrow < cn) {
                    float w = wt_s[lrow];
                    atomicAdd(&out[(size_t)tok_s[lrow] * DIM + d],
                              w * (acc[mi][ni][r] + bv));
                }
            }
        }
    }
}

// ------------------------------------------------- round-1 fp32 fallback ----
#define TN 16
#define HC 256
#define NCHUNK (HID / HC)

__global__ __launch_bounds__(256) void gating_fb_kernel(
    const float* __restrict__ x, const float* __restrict__ Wg,
    const float* __restrict__ bg,
    int* __restrict__ cnt, int* __restrict__ btok, float* __restrict__ bwt,
    float* __restrict__ usage)
{
    int wave = threadIdx.x >> 6;
    int lane = threadIdx.x & 63;
    int n = blockIdx.x * 4 + wave;
    float acc[NEXP];
#pragma unroll
    for (int e = 0; e < NEXP; ++e) acc[e] = 0.f;
    for (int d = lane; d < DIM; d += 64) {
        float xv = x[n * DIM + d];
        float4 wa = *(const float4*)&Wg[d * NEXP];
        float4 wb = *(const float4*)&Wg[d * NEXP + 4];
        acc[0] += xv * wa.x; acc[1] += xv * wa.y;
        acc[2] += xv * wa.z; acc[3] += xv * wa.w;
        acc[4] += xv * wb.x; acc[5] += xv * wb.y;
        acc[6] += xv * wb.z; acc[7] += xv * wb.w;
    }
#pragma unroll
    for (int m = 32; m >= 1; m >>= 1)
#pragma unroll
        for (int e = 0; e < NEXP; ++e)
            acc[e] += __shfl_xor(acc[e], m, 64);
    if (lane == 0) {
        float l[NEXP];
#pragma unroll
        for (int e = 0; e < NEXP; ++e) l[e] = acc[e] + bg[e];
        int i0 = 0;
#pragma unroll
        for (int e = 1; e < NEXP; ++e) if (l[e] > l[i0]) i0 = e;
        int i1 = (i0 == 0) ? 1 : 0;
#pragma unroll
        for (int e = 0; e < NEXP; ++e)
            if (e != i0 && l[e] > l[i1]) i1 = e;
        float w0 = 1.f / (1.f + expf(l[i1] - l[i0]));
        float w1 = 1.f - w0;
        int p0 = atomicAdd(&cnt[i0], 1);
        btok[i0 * N_TOK + p0] = n; bwt[i0 * N_TOK + p0] = w0;
        int p1 = atomicAdd(&cnt[i1], 1);
        btok[i1 * N_TOK + p1] = n; bwt[i1 * N_TOK + p1] = w1;
        atomicAdd(&usage[i0], w0);
        atomicAdd(&usage[i1], w1);
    }
}

__global__ __launch_bounds__(256) void expert_fb_kernel(
    const float* __restrict__ x, const float* __restrict__ W1,
    const float* __restrict__ b1, const float* __restrict__ W2,
    const float* __restrict__ b2, const int* __restrict__ cnt,
    const int* __restrict__ btok, const float* __restrict__ bwt,
    float* __restrict__ out)
{
    __shared__ float xs[TN][DIM];
    __shared__ float h1s[TN][HC];
    __shared__ int   tok_s[TN];
    __shared__ float wt_s[TN];
    int e = blockIdx.x >> 8;
    int tile = blockIdx.x & 255;
    int cn = cnt[e];
    int n0 = tile * TN;
    if (n0 >= cn) return;
    int nt = min(TN, cn - n0);
    int tid = threadIdx.x;
    if (tid < TN) {
        if (tid < nt) { tok_s[tid] = btok[e * N_TOK + n0 + tid]; wt_s[tid] = bwt[e * N_TOK + n0 + tid]; }
        else          { tok_s[tid] = 0; wt_s[tid] = 0.f; }
    }
    __syncthreads();
    for (int idx = tid; idx < TN * DIM; idx += 256) {
        int t = idx >> 9, d = idx & 511;
        xs[t][d] = (t < nt) ? x[tok_s[t] * DIM + d] : 0.f;
    }
    const float* W1e = W1 + (size_t)e * DIM * HID;
    const float* W2e = W2 + (size_t)e * HID * DIM;
    int tg = tid >> 6, lane = tid & 63;
    float oacc[4][8];
    {
        float4 ba = *(const float4*)&b2[e * DIM + lane * 8];
        float4 bb = *(const float4*)&b2[e * DIM + lane * 8 + 4];
#pragma unroll
        for (int ti = 0; ti < 4; ++ti) {
            oacc[ti][0] = ba.x; oacc[ti][1] = ba.y; oacc[ti][2] = ba.z; oacc[ti][3] = ba.w;
            oacc[ti][4] = bb.x; oacc[ti][5] = bb.y; oacc[ti][6] = bb.z; oacc[ti][7] = bb.w;
        }
    }
    __syncthreads();
    for (int ch = 0; ch < NCHUNK; ++ch) {
        int h0 = ch * HC;
        float f[4][4];
        {
            float4 b1v = *(const float4*)&b1[e * HID + h0 + lane * 4];
#pragma unroll
            for (int ti = 0; ti < 4; ++ti) {
                f[ti][0] = b1v.x; f[ti][1] = b1v.y; f[ti][2] = b1v.z; f[ti][3] = b1v.w;
            }
        }
        for (int d = 0; d < DIM; ++d) {
            float4 w1v = *(const float4*)&W1e[(size_t)d * HID + h0 + lane * 4];
#pragma unroll
            for (int ti = 0; ti < 4; ++ti) {
                float xv = xs[tg + 4 * ti][d];
                f[ti][0] += xv * w1v.x; f[ti][1] += xv * w1v.y;
                f[ti][2] += xv * w1v.z; f[ti][3] += xv * w1v.w;
            }
        }
        __syncthreads();
#pragma unroll
        for (int ti = 0; ti < 4; ++ti)
            *(float4*)&h1s[tg + 4 * ti][lane * 4] = make_float4(f[ti][0], f[ti][1], f[ti][2], f[ti][3]);
        __syncthreads();
        for (int j = 0; j < HC; ++j) {
            const float* w2row = &W2e[(size_t)(h0 + j) * DIM + lane * 8];
            float4 wa = *(const float4*)w2row;
            float4 wb = *(const float4*)(w2row + 4);
#pragma unroll
            for (int ti = 0; ti < 4; ++ti) {
                float hv = h1s[tg + 4 * ti][j];
                oacc[ti][0] += hv * wa.x; oacc[ti][1] += hv * wa.y;
                oacc[ti][2] += hv * wa.z; oacc[ti][3] += hv * wa.w;
                oacc[ti][4] += hv * wb.x; oacc[ti][5] += hv * wb.y;
                oacc[ti][6] += hv * wb.z; oacc[ti][7] += hv * wb.w;
            }
        }
    }
#pragma unroll
    for (int ti = 0; ti < 4; ++ti) {
        int t = tg + 4 * ti;
        if (t < nt) {
            float w = wt_s[t];
            float* o = &out[(size_t)tok_s[t] * DIM + lane * 8];
#pragma unroll
            for (int c = 0; c < 8; ++c)
                atomicAdd(&o[c], w * oacc[ti][c]);
        }
    }
}

// ------------------------------------------------------------------ host ----
extern "C" void kernel_launch(void* const* d_in, const int* in_sizes, int n_in,
                              void* d_out, int out_size, void* d_ws, size_t ws_size,
                              hipStream_t stream) {
    const float* x  = (const float*)d_in[0];
    const float* Wg = (const float*)d_in[1];
    const float* bg = (const float*)d_in[2];
    const float* W1 = (const float*)d_in[3];
    const float* b1 = (const float*)d_in[4];
    const float* W2 = (const float*)d_in[5];
    const float* b2 = (const float*)d_in[6];

    float* out   = (float*)d_out;
    float* usage = out + (size_t)N_TOK * DIM;

    // ws layout (bf16 path)
    char* ws = (char*)d_ws;
    int*   cnt  = (int*)(ws + 0);     // 8 ints
    int*   fill = (int*)(ws + 32);    // 8 ints
    int*   offs = (int*)(ws + 64);    // 8 ints
    unsigned short* tile_tab = (unsigned short*)(ws + 96);  // 72 ushorts -> 240
    int*   ntile = (int*)(ws + 240);
    int*   te   = (int*)(ws + 256);
    float* tw   = (float*)(ws + 33024);
    int*   btok = (int*)(ws + 65792);
    float* bwt  = (float*)(ws + 98560);
    unsigned short* Xb  = (unsigned short*)(ws + 131328);
    unsigned short* W1t = (unsigned short*)(ws + 4325632);
    unsigned short* W2t = (unsigned short*)(ws + 21102848);
    unsigned short* H1  = (unsigned short*)(ws + 37880064);
    const size_t WS_NEED = 71434496ULL;

    hipMemsetAsync(d_out, 0, (size_t)(N_TOK * DIM + NEXP) * sizeof(float), stream);

    if (ws_size >= WS_NEED) {
        hipMemsetAsync(cnt, 0, 32, stream);
        cvtx_kernel<<<N_TOK * DIM / 1024, 256, 0, stream>>>(x, Xb);
        transpose_cvt_kernel<<<dim3(DIM / 64, HID / 64, NEXP), 256, 0, stream>>>(W1, W1t, DIM, HID);
        transpose_cvt_kernel<<<dim3(HID / 64, DIM / 64, NEXP), 256, 0, stream>>>(W2, W2t, HID, DIM);
        gating_kernel<<<N_TOK / 64, 256, 0, stream>>>(x, Wg, bg, cnt, te, tw, usage);
        prefix_kernel<<<1, 64, 0, stream>>>(cnt, offs, fill, tile_tab, ntile);
        scatter_kernel<<<N_TOK / 256, 256, 0, stream>>>(te, tw, offs, fill, btok, bwt);
        gemm1_kernel<<<dim3(MAXTILE, HID / 128), 256, 0, stream>>>(
            Xb, W1t, b1, cnt, offs, btok, tile_tab, ntile, H1);
        gemm2_kernel<<<dim3(MAXTILE, DIM / 128, KSPLIT), 256, 0, stream>>>(
            H1, W2t, b2, cnt, offs, btok, bwt, tile_tab, ntile, out);
    } else {
        // round-1 fp32 fallback (verified)
        int*   fcnt  = (int*)d_ws;
        int*   fbtok = (int*)((char*)d_ws + 256);
        float* fbwt  = (float*)((char*)d_ws + 256 + (size_t)NEXP * N_TOK * sizeof(int));
        hipMemsetAsync(d_ws, 0, 256, stream);
        gating_fb_kernel<<<N_TOK / 4, 256, 0, stream>>>(x, Wg, bg, fcnt, fbtok, fbwt, usage);
        expert_fb_kernel<<<NEXP * (N_TOK / TN), 256, 0, stream>>>(
            x, W1, b1, W2, b2, fcnt, fbtok, fbwt, out);
    }
}